// Round 1
// baseline (229.867 us; speedup 1.0000x reference)
//
#include <hip/hip_runtime.h>

// Barrel shift right (toward higher index) each 64-float row by
// S = sum_j shift[j] * 2^(5-j)  (shift bits are exactly 0.0/1.0).
// out[row][k] = (k >= S) ? data[row][k-S] : 0.
//
// Wave layout: 4 rows per wave, 16 lanes per row, float4 per lane.
//   lane = g*16 + t16 ; g = row-in-wave (0..3), t16 covers row positions t16*4..t16*4+3.

__global__ __launch_bounds__(256)
void BarrelShifterRight64_kernel(const float* __restrict__ data,
                                 const float* __restrict__ shift,
                                 float* __restrict__ out,
                                 int nwrows /* = B/4 groups of 4 rows */) {
    const int lane = threadIdx.x & 63;
    const int wib  = threadIdx.x >> 6;
    const int wpb  = blockDim.x >> 6;                 // waves per block (4)
    const int nw   = gridDim.x * wpb;                 // total waves
    int w = blockIdx.x * wpb + wib;

    const float4* __restrict__ d4 = (const float4*)data;
    float4* __restrict__       o4 = (float4*)out;

    const int g   = lane >> 4;       // which of the 4 rows this lane serves
    const int t16 = lane & 15;       // 16-lane position within the row

    for (; w < nwrows; w += nw) {
        // coalesced 1KiB load: 4 rows (256 floats) per wave
        float4 val = d4[w * 64 + lane];

        // 24 contiguous shift floats for the wave's 4 rows -> one ballot
        float sv = 0.0f;
        if (lane < 24) sv = shift[w * 24 + lane];
        unsigned long long b = __ballot(sv > 0.5f);

        // per-group 6-bit MSB-first control word -> integer shift S
        unsigned sub = (unsigned)(b >> (6 * g)) & 63u;
        int S = (int)(__brev(sub) >> 26);            // bit j -> weight 1<<(5-j)

        // source positions needed by this lane: q0..q0+3  (q0 = p0 - S)
        int q0  = t16 * 4 - S;
        int la  = q0 >> 2;                            // arithmetic shift: floor
        int laC = la < 0 ? 0 : la;
        int lb  = la + 1 > 15 ? 15 : la + 1;
        int baseA = g * 16 + laC;
        int baseB = g * 16 + lb;

        // fetch the (at most) two source lanes' float4s
        float e0 = __shfl(val.x, baseA, 64);
        float e1 = __shfl(val.y, baseA, 64);
        float e2 = __shfl(val.z, baseA, 64);
        float e3 = __shfl(val.w, baseA, 64);
        float e4 = __shfl(val.x, baseB, 64);
        float e5 = __shfl(val.y, baseB, 64);
        float e6 = __shfl(val.z, baseB, 64);

        // funnel-select at sub-float4 alignment t = q0 & 3 (uniform per row)
        int t = q0 & 3;
        bool t1 = (t == 1), t2 = (t == 2), t3 = (t == 3);
        float o0 = t3 ? e3 : (t2 ? e2 : (t1 ? e1 : e0));
        float o1 = t3 ? e4 : (t2 ? e3 : (t1 ? e2 : e1));
        float o2 = t3 ? e5 : (t2 ? e4 : (t1 ? e3 : e2));
        float o3 = t3 ? e6 : (t2 ? e5 : (t1 ? e4 : e3));

        // zero-fill the low end: elem j valid iff q0 + j >= 0
        o0 = (q0 >= 0)  ? o0 : 0.0f;
        o1 = (q0 >= -1) ? o1 : 0.0f;
        o2 = (q0 >= -2) ? o2 : 0.0f;
        o3 = (q0 >= -3) ? o3 : 0.0f;

        o4[w * 64 + lane] = make_float4(o0, o1, o2, o3);
    }
}

extern "C" void kernel_launch(void* const* d_in, const int* in_sizes, int n_in,
                              void* d_out, int out_size, void* d_ws, size_t ws_size,
                              hipStream_t stream) {
    const float* data  = (const float*)d_in[0];
    const float* shift = (const float*)d_in[1];
    float* out = (float*)d_out;

    const int nrows  = in_sizes[0] / 64;   // B
    const int nwrows = nrows / 4;          // 4 rows per wave

    const int block = 256;
    const int grid  = 2048;                // 8192 waves, grid-stride
    BarrelShifterRight64_kernel<<<grid, block, 0, stream>>>(data, shift, out, nwrows);
}

// Round 3
// 203.217 us; speedup vs baseline: 1.1311x; 1.1311x over previous
//
#include <hip/hip_runtime.h>

// Barrel shift right (toward higher index) each 64-float row by
// S = sum_j shift[j] * 2^(5-j)  (shift entries are exactly 0.0/1.0).
// out[row][k] = (k >= S) ? data[row][k-S] : 0.
//
// Wave layout: 4 rows per wave, 16 lanes per row, float4 per lane.
// S is row-uniform, so q0&3 (sub-float4 alignment) is row-uniform: each
// source lane pre-rotates its own float4 in-lane, then one ds_bpermute
// per output element fetches the right word. 4 shfl/row instead of 7.

typedef float f4 __attribute__((ext_vector_type(4)));  // native vector: OK for nontemporal builtins

__device__ __forceinline__ f4 rowshift(f4 val, unsigned long long b,
                                       int g, int t16) {
    unsigned sub = (unsigned)(b >> (6 * g)) & 63u;
    int S = (int)(__brev(sub) >> 26);        // MSB-first control word
    int q0 = t16 * 4 - S;                    // first source position
    int t = q0 & 3;                          // row-uniform sub-word alignment

    // in-lane rotate-left of val by t: s[j] = val[(t+j)&3]
    bool b0 = (t & 1) != 0, b1 = (t & 2) != 0;
    float r0 = b1 ? val.z : val.x;
    float r1 = b1 ? val.w : val.y;
    float r2 = b1 ? val.x : val.z;
    float r3 = b1 ? val.y : val.w;
    float s0 = b0 ? r1 : r0;
    float s1 = b0 ? r2 : r1;
    float s2 = b0 ? r3 : r2;
    float s3 = b0 ? r0 : r3;

    // source lane (within the row's 16 lanes) for each output element
    int la0 = (q0    ) >> 2;
    int la1 = (q0 + 1) >> 2;
    int la2 = (q0 + 2) >> 2;
    int la3 = (q0 + 3) >> 2;
    la0 = la0 < 0 ? 0 : la0;
    la1 = la1 < 0 ? 0 : la1;
    la2 = la2 < 0 ? 0 : la2;
    la3 = la3 < 0 ? 0 : la3;
    int base = g * 16;

    float o0 = __shfl(s0, base + la0, 64);
    float o1 = __shfl(s1, base + la1, 64);
    float o2 = __shfl(s2, base + la2, 64);
    float o3 = __shfl(s3, base + la3, 64);

    o0 = (q0 >= 0)  ? o0 : 0.0f;
    o1 = (q0 >= -1) ? o1 : 0.0f;
    o2 = (q0 >= -2) ? o2 : 0.0f;
    o3 = (q0 >= -3) ? o3 : 0.0f;
    f4 r;
    r.x = o0; r.y = o1; r.z = o2; r.w = o3;
    return r;
}

__global__ __launch_bounds__(256)
void BarrelShifterRight64_kernel(const float* __restrict__ data,
                                 const float* __restrict__ shift,
                                 float* __restrict__ out,
                                 int nwrows) {
    const int lane = threadIdx.x & 63;
    const int wib  = threadIdx.x >> 6;
    const int wpb  = blockDim.x >> 6;
    const int nw   = gridDim.x * wpb;
    const int w0   = blockIdx.x * wpb + wib;

    const f4* __restrict__ d4 = (const f4*)data;
    f4* __restrict__       o4 = (f4*)out;

    const int g   = lane >> 4;
    const int t16 = lane & 15;

    for (int w = w0; w < nwrows; w += 2 * nw) {
        const int w1 = w + nw;
        const bool have1 = w1 < nwrows;

        // issue both independent row-set loads up front (MLP)
        f4 vA = __builtin_nontemporal_load(&d4[w * 64 + lane]);
        float svA = (lane < 24) ? shift[w * 24 + lane] : 0.0f;

        f4 vB = (f4)(0.0f);
        float svB = 0.0f;
        if (have1) {
            vB  = __builtin_nontemporal_load(&d4[w1 * 64 + lane]);
            svB = (lane < 24) ? shift[w1 * 24 + lane] : 0.0f;
        }

        unsigned long long bA = __ballot(svA > 0.5f);
        f4 oA = rowshift(vA, bA, g, t16);
        __builtin_nontemporal_store(oA, &o4[w * 64 + lane]);

        if (have1) {
            unsigned long long bB = __ballot(svB > 0.5f);
            f4 oB = rowshift(vB, bB, g, t16);
            __builtin_nontemporal_store(oB, &o4[w1 * 64 + lane]);
        }
    }
}

extern "C" void kernel_launch(void* const* d_in, const int* in_sizes, int n_in,
                              void* d_out, int out_size, void* d_ws, size_t ws_size,
                              hipStream_t stream) {
    const float* data  = (const float*)d_in[0];
    const float* shift = (const float*)d_in[1];
    float* out = (float*)d_out;

    const int nrows  = in_sizes[0] / 64;   // B
    const int nwrows = nrows / 4;          // 4 rows per wave

    const int block = 256;
    const int grid  = 2048;                // 8192 waves, grid-stride, unroll x2
    BarrelShifterRight64_kernel<<<grid, block, 0, stream>>>(data, shift, out, nwrows);
}